// Round 7
// baseline (176.988 us; speedup 1.0000x reference)
//
#include <hip/hip_runtime.h>

// ParaModel_69664369541839: match = v1 @ v2^T [B,L1,L2]; masked row/col max;
// s = -max/100 masked; softmax; attention-pool p1,p2; cosine(p1,p2).
// B=128, L1=L2=256, D=768, fp32 in/out.
//
// R7: FULL FUSION. The inter-phase dependency is only per-batch (batch b's
// softmax needs only its 4 match blocks), so: 512 blocks; each does its
// 128x128 match tile (R6 loop), stores PARTIAL row/col maxes (plain stores,
// no global atomics), bumps cnt[b]; the LAST of the 4 (atomicAdd returns 3 —
// no spinning, no deadlock risk) runs phase 2: dual softmax + pool + cosine
// in-block. Early batches' phase-2 overlaps later batches' match phase.
// Eliminates: K2 launch (~18us serialized), K3 launch, 256KB memset, pout.
// Only a 512B counter memset + one kernel remain.

#define B_   128
#define L_   256
#define D_   768
#define NEGV (-10000.0f)

typedef _Float16 f16x8 __attribute__((ext_vector_type(8)));
typedef __fp16   h16x2 __attribute__((ext_vector_type(2)));
typedef float    f32x4 __attribute__((ext_vector_type(4)));

#define BT   128          // l1/l2 tile
#define BKF  64           // fp32 k-elems per staged tile (2 MFMA K-steps)
#define NKT  (D_ / BKF)   // 12
#define LDH  72           // halves per LDS row (144B: uniform bank spread)
#define NBH  (BT * LDH)   // halves per operand buffer (9216)

__device__ __forceinline__ unsigned fmap(float f) {
    unsigned u = __float_as_uint(f);
    return (u & 0x80000000u) ? ~u : (u | 0x80000000u);   // monotone float->uint
}
__device__ __forceinline__ float fdecode(unsigned u) {
    return __uint_as_float((u & 0x80000000u) ? (u ^ 0x80000000u) : ~u);
}
__device__ __forceinline__ float wred_max(float v) {
    #pragma unroll
    for (int o = 32; o; o >>= 1) v = fmaxf(v, __shfl_xor(v, o));
    return v;
}
__device__ __forceinline__ float wred_sum(float v) {
    #pragma unroll
    for (int o = 32; o; o >>= 1) v += __shfl_xor(v, o);
    return v;
}

__device__ __forceinline__ f16x8 cvt8(float4 a, float4 b) {
    union { h16x2 h2[4]; f16x8 h8; } u;
    u.h2[0] = __builtin_amdgcn_cvt_pkrtz(a.x, a.y);
    u.h2[1] = __builtin_amdgcn_cvt_pkrtz(a.z, a.w);
    u.h2[2] = __builtin_amdgcn_cvt_pkrtz(b.x, b.y);
    u.h2[3] = __builtin_amdgcn_cvt_pkrtz(b.z, b.w);
    return u.h8;
}

__global__ __launch_bounds__(512, 2)
void k_fused(const float* __restrict__ v1, const float* __restrict__ m1,
             const float* __restrict__ v2, const float* __restrict__ m2,
             float* __restrict__ rmax_p, float* __restrict__ cmax_p,
             unsigned* __restrict__ cnt, float* __restrict__ out)
{
    // 72 KB staging buffer, aliased by phase 2 (attn + pooled vectors)
    __shared__ __align__(16) char smem[2 * 2 * NBH * 2];   // 73728 B
    __shared__ unsigned rU[BT], cU[BT];
    __shared__ float m1s[BT], m2s[BT];
    __shared__ float sred[8], sd[8], sa[8], sc2[8];
    __shared__ int islast;

    _Float16* AsB = (_Float16*)smem;              // [2][NBH]
    _Float16* BsB = (_Float16*)(smem + 2 * NBH * 2);

    // bijective XCD swizzle: a batch's 4 blocks (and its ws partials) on one XCD
    const int bid = blockIdx.x;
    const int wg  = (bid & 7) * 64 + (bid >> 3);
    const int b = wg >> 2, ti = (wg >> 1) & 1, tj = wg & 1;

    const int t = threadIdx.x;
    const int lane = t & 63, w = t >> 6;
    const int wr = w >> 1, wc = w & 1;            // wave sub-tile: 32 rows x 64 cols
    const int fr = lane & 15, fg = lane >> 4;

    if (t < BT) {
        rU[t] = 0u; cU[t] = 0u;                   // 0 == -inf under fmap
        m1s[t] = m1[b * L_ + ti * BT + t];
        m2s[t] = m2[b * L_ + tj * BT + t];
    }

    // staging geometry: thread t owns row (t>>2), fp32 cols [c4*16, +16)
    const int grow = t >> 2;
    const int c4   = t & 3;
    const float* ga = v1 + ((size_t)b * L_ + ti * BT + grow) * D_ + c4 * 16;
    const float* gb = v2 + ((size_t)b * L_ + tj * BT + grow) * D_ + c4 * 16;

    float4 ra[4], rb[4];

    #define GLOAD(kt) do {                                                    \
        const float* A_ = ga + (kt) * BKF;                                    \
        const float* C_ = gb + (kt) * BKF;                                    \
        ra[0] = *(const float4*)(A_);      ra[1] = *(const float4*)(A_ + 4);  \
        ra[2] = *(const float4*)(A_ + 8);  ra[3] = *(const float4*)(A_ + 12); \
        rb[0] = *(const float4*)(C_);      rb[1] = *(const float4*)(C_ + 4);  \
        rb[2] = *(const float4*)(C_ + 8);  rb[3] = *(const float4*)(C_ + 12); \
    } while (0)

    #define DSWRITE(buf) do {                                                 \
        _Float16* da = AsB + (buf) * NBH + grow * LDH + c4 * 16;              \
        _Float16* db = BsB + (buf) * NBH + grow * LDH + c4 * 16;              \
        *(f16x8*)da       = cvt8(ra[0], ra[1]);                               \
        *(f16x8*)(da + 8) = cvt8(ra[2], ra[3]);                               \
        *(f16x8*)db       = cvt8(rb[0], rb[1]);                               \
        *(f16x8*)(db + 8) = cvt8(rb[2], rb[3]);                               \
    } while (0)

    f32x4 acc[2][4] = {};
    GLOAD(0);
    DSWRITE(0);
    __syncthreads();
    int cur = 0;
    for (int kt = 0; kt < NKT; ++kt) {
        if (kt + 1 < NKT) GLOAD(kt + 1);          // issue early (under MFMA)
        __builtin_amdgcn_sched_barrier(0);
        #pragma unroll
        for (int ks = 0; ks < 2; ++ks) {
            f16x8 af[2], bf[4];
            #pragma unroll
            for (int i = 0; i < 2; ++i) {
                int r1 = wr * 32 + i * 16 + fr;
                af[i] = *(const f16x8*)&AsB[cur * NBH + r1 * LDH + ks * 32 + fg * 8];
            }
            #pragma unroll
            for (int j = 0; j < 4; ++j) {
                int r2 = wc * 64 + j * 16 + fr;
                bf[j] = *(const f16x8*)&BsB[cur * NBH + r2 * LDH + ks * 32 + fg * 8];
            }
            #pragma unroll
            for (int i = 0; i < 2; ++i)
                #pragma unroll
                for (int j = 0; j < 4; ++j)
                    acc[i][j] = __builtin_amdgcn_mfma_f32_16x16x32_f16(af[i], bf[j], acc[i][j], 0, 0, 0);
        }
        __builtin_amdgcn_sched_barrier(0);
        if (kt + 1 < NKT) DSWRITE(cur ^ 1);       // vmcnt wait lands here only
        __syncthreads();
        cur ^= 1;
    }
    #undef GLOAD
    #undef DSWRITE

    // block-local masked row/col max (C/D layout: row = fg*4+reg +16i, col = fr +16j)
    #pragma unroll
    for (int i = 0; i < 2; ++i)
        #pragma unroll
        for (int r = 0; r < 4; ++r) {
            int row = wr * 32 + i * 16 + fg * 4 + r;
            bool rv = m1s[row] > 0.f;
            float mx = NEGV;
            #pragma unroll
            for (int j = 0; j < 4; ++j) {
                int col = wc * 64 + j * 16 + fr;
                float vv = (rv && m2s[col] > 0.f) ? acc[i][j][r] : NEGV;
                mx = fmaxf(mx, vv);
            }
            atomicMax(&rU[row], fmap(mx));
        }
    #pragma unroll
    for (int j = 0; j < 4; ++j) {
        int col = wc * 64 + j * 16 + fr;
        bool cv = m2s[col] > 0.f;
        float mx = NEGV;
        #pragma unroll
        for (int i = 0; i < 2; ++i)
            #pragma unroll
            for (int r = 0; r < 4; ++r) {
                int row = wr * 32 + i * 16 + fg * 4 + r;
                float vv = (cv && m1s[row] > 0.f) ? acc[i][j][r] : NEGV;
                mx = fmaxf(mx, vv);
            }
        atomicMax(&cU[col], fmap(mx));
    }
    __syncthreads();

    // publish PARTIAL maxes (plain stores; each slot written by exactly one block)
    if (t < BT)            rmax_p[((size_t)b * 2 + tj) * L_ + ti * BT + t]      = fdecode(rU[t]);
    else if (t < 2 * BT)   cmax_p[((size_t)b * 2 + ti) * L_ + tj * BT + (t - BT)] = fdecode(cU[t - BT]);
    __threadfence();                              // device-scope release
    __syncthreads();
    if (t == 0) islast = (atomicAdd(&cnt[b], 1u) == 3u);
    __syncthreads();
    if (!islast) return;
    __threadfence();                              // device-scope acquire

    // ---- phase 2 (one block per batch): softmax both sides + pool + cosine ----
    float* attnb = (float*)smem;                  // [2][256]  (aliases AsB)
    float* pbuf  = (float*)(smem + 2048);         // [2][768]
    const int h = t >> 8;                         // side: 0 (v1/rows) or 1 (v2/cols)
    const int l = t & 255;

    volatile const float* rp = rmax_p + (size_t)b * 2 * L_;
    volatile const float* cp = cmax_p + (size_t)b * 2 * L_;
    float mkv = (h ? m2 : m1)[b * L_ + l];
    float mxv = h ? fmaxf(cp[l], cp[L_ + l]) : fmaxf(rp[l], rp[L_ + l]);
    float s = (mkv > 0.f) ? (-mxv * 0.01f) : NEGV;

    // softmax within each 256-thread half (waves 0-3 = side 0, waves 4-7 = side 1)
    float wm = wred_max(s);
    if (lane == 0) sred[w] = wm;
    __syncthreads();
    float mx = fmaxf(fmaxf(sred[h * 4 + 0], sred[h * 4 + 1]),
                     fmaxf(sred[h * 4 + 2], sred[h * 4 + 3]));
    float e = expf(s - mx);
    __syncthreads();
    float wsum = wred_sum(e);
    if (lane == 0) sred[w] = wsum;
    __syncthreads();
    float sum = sred[h * 4 + 0] + sred[h * 4 + 1] + sred[h * 4 + 2] + sred[h * 4 + 3];
    attnb[h * 256 + l] = e / sum;
    __syncthreads();

    // pool: side h, dims chunk*256+l (coalesced across the wave per l-row)
    const float* vsrc = (h ? v2 : v1) + (size_t)b * L_ * D_;
    const float* an = attnb + h * 256;
    #pragma unroll
    for (int chunk = 0; chunk < 3; ++chunk) {
        int d = chunk * 256 + l;
        const float* vb = vsrc + d;
        float p = 0.f;
        #pragma unroll 8
        for (int ll = 0; ll < L_; ++ll) p += an[ll] * vb[(size_t)ll * D_];
        pbuf[h * 768 + d] = p;
    }
    __syncthreads();

    // cosine similarity
    float dot = 0.f, n1 = 0.f, n2 = 0.f;
    for (int d = t; d < D_; d += 512) {
        float a = pbuf[d], c = pbuf[768 + d];
        dot += a * c; n1 += a * a; n2 += c * c;
    }
    dot = wred_sum(dot); n1 = wred_sum(n1); n2 = wred_sum(n2);
    if (lane == 0) { sd[w] = dot; sa[w] = n1; sc2[w] = n2; }
    __syncthreads();
    if (t == 0) {
        float dd = 0.f, aa = 0.f, cc = 0.f;
        #pragma unroll
        for (int i = 0; i < 8; ++i) { dd += sd[i]; aa += sa[i]; cc += sc2[i]; }
        out[b] = dd / (fmaxf(sqrtf(aa), 1e-8f) * fmaxf(sqrtf(cc), 1e-8f));
    }
}

extern "C" void kernel_launch(void* const* d_in, const int* in_sizes, int n_in,
                              void* d_out, int out_size, void* d_ws, size_t ws_size,
                              hipStream_t stream)
{
    const float* v1 = (const float*)d_in[0];
    const float* m1 = (const float*)d_in[1];
    const float* v2 = (const float*)d_in[2];
    const float* m2 = (const float*)d_in[3];
    float* out = (float*)d_out;

    unsigned* cnt    = (unsigned*)d_ws;                    // [B] arrival counters
    float*    rmax_p = (float*)((char*)d_ws + 512);        // [B][2][256] row-max partials
    float*    cmax_p = rmax_p + (size_t)B_ * 2 * L_;       // [B][2][256] col-max partials

    (void)hipMemsetAsync(d_ws, 0, 512, stream);            // counters only

    k_fused<<<dim3(4 * B_), 512, 0, stream>>>(v1, m1, v2, m2, rmax_p, cmax_p, cnt, out);
}

// Round 8
// 174.420 us; speedup vs baseline: 1.0147x; 1.0147x over previous
//
#include <hip/hip_runtime.h>

// ParaModel_69664369541839: match = v1 @ v2^T [B,L1,L2]; masked row/col max;
// s = -max/100 masked; softmax; attention-pool p1,p2; cosine(p1,p2).
// B=128, L1=L2=256, D=768, fp32 in/out.
//
// R8: fusion with FIXED work partition. R7 concentrated phase 2 (201MB pool)
// into 128 "last" blocks -> serialized tail, +100us. Now ALL 4 blocks of a
// batch run phase 2: grid = 512 = exactly 2 blocks/CU x 256 CU (LDS 76KB,
// VGPR<=96) so all blocks are co-resident and a spin on cnt[b]==4 cannot
// deadlock (siblings' bids span only 24 even under sliding-window dispatch).
// Each block: both softmaxes (redundant, cheap) + pools its 192-dim chunk of
// BOTH p1,p2 + partial cosine sums (plain stores, deterministic); last
// arriver of cnt2[b] combines 12 scalars -> out[b].

#define B_   128
#define L_   256
#define D_   768
#define NEGV (-10000.0f)

typedef _Float16 f16x8 __attribute__((ext_vector_type(8)));
typedef __fp16   h16x2 __attribute__((ext_vector_type(2)));
typedef float    f32x4 __attribute__((ext_vector_type(4)));

#define BT   128          // l1/l2 tile
#define BKF  64           // fp32 k-elems per staged tile (2 MFMA K-steps)
#define NKT  (D_ / BKF)   // 12
#define LDH  72           // halves per LDS row (144B: uniform bank spread)
#define NBH  (BT * LDH)   // halves per operand buffer (9216)

__device__ __forceinline__ unsigned fmap(float f) {
    unsigned u = __float_as_uint(f);
    return (u & 0x80000000u) ? ~u : (u | 0x80000000u);   // monotone float->uint
}
__device__ __forceinline__ float fdecode(unsigned u) {
    return __uint_as_float((u & 0x80000000u) ? (u ^ 0x80000000u) : ~u);
}
__device__ __forceinline__ float wred_max(float v) {
    #pragma unroll
    for (int o = 32; o; o >>= 1) v = fmaxf(v, __shfl_xor(v, o));
    return v;
}
__device__ __forceinline__ float wred_sum(float v) {
    #pragma unroll
    for (int o = 32; o; o >>= 1) v += __shfl_xor(v, o);
    return v;
}

__device__ __forceinline__ f16x8 cvt8(float4 a, float4 b) {
    union { h16x2 h2[4]; f16x8 h8; } u;
    u.h2[0] = __builtin_amdgcn_cvt_pkrtz(a.x, a.y);
    u.h2[1] = __builtin_amdgcn_cvt_pkrtz(a.z, a.w);
    u.h2[2] = __builtin_amdgcn_cvt_pkrtz(b.x, b.y);
    u.h2[3] = __builtin_amdgcn_cvt_pkrtz(b.z, b.w);
    return u.h8;
}

__global__ __launch_bounds__(512, 2)
void k_fused(const float* __restrict__ v1, const float* __restrict__ m1,
             const float* __restrict__ v2, const float* __restrict__ m2,
             float* __restrict__ rmax_p, float* __restrict__ cmax_p,
             float* __restrict__ gpart,
             unsigned* __restrict__ cnt, unsigned* __restrict__ cnt2,
             float* __restrict__ out)
{
    // 72 KB staging buffer, aliased by phase 2 (attn + pooled chunks)
    __shared__ __align__(16) char smem[2 * 2 * NBH * 2];   // 73728 B
    __shared__ unsigned rU[BT], cU[BT];
    __shared__ float m1s[BT], m2s[BT];
    __shared__ float sred[8], sd[8], sa[8], sc2[8];

    _Float16* AsB = (_Float16*)smem;              // [2][NBH]
    _Float16* BsB = (_Float16*)(smem + 2 * NBH * 2);

    // bijective XCD swizzle: a batch's 4 blocks (and its ws partials) on one XCD
    const int bid = blockIdx.x;
    const int wg  = (bid & 7) * 64 + (bid >> 3);
    const int b = wg >> 2, ti = (wg >> 1) & 1, tj = wg & 1;

    const int t = threadIdx.x;
    const int lane = t & 63, w = t >> 6;
    const int wr = w >> 1, wc = w & 1;            // wave sub-tile: 32 rows x 64 cols
    const int fr = lane & 15, fg = lane >> 4;

    if (t < BT) {
        rU[t] = 0u; cU[t] = 0u;                   // 0 == -inf under fmap
        m1s[t] = m1[b * L_ + ti * BT + t];
        m2s[t] = m2[b * L_ + tj * BT + t];
    }

    // staging geometry: thread t owns row (t>>2), fp32 cols [c4*16, +16)
    const int grow = t >> 2;
    const int c4   = t & 3;
    const float* ga = v1 + ((size_t)b * L_ + ti * BT + grow) * D_ + c4 * 16;
    const float* gb = v2 + ((size_t)b * L_ + tj * BT + grow) * D_ + c4 * 16;

    float4 ra[4], rb[4];

    #define GLOAD(kt) do {                                                    \
        const float* A_ = ga + (kt) * BKF;                                    \
        const float* C_ = gb + (kt) * BKF;                                    \
        ra[0] = *(const float4*)(A_);      ra[1] = *(const float4*)(A_ + 4);  \
        ra[2] = *(const float4*)(A_ + 8);  ra[3] = *(const float4*)(A_ + 12); \
        rb[0] = *(const float4*)(C_);      rb[1] = *(const float4*)(C_ + 4);  \
        rb[2] = *(const float4*)(C_ + 8);  rb[3] = *(const float4*)(C_ + 12); \
    } while (0)

    #define DSWRITE(buf) do {                                                 \
        _Float16* da = AsB + (buf) * NBH + grow * LDH + c4 * 16;              \
        _Float16* db = BsB + (buf) * NBH + grow * LDH + c4 * 16;              \
        *(f16x8*)da       = cvt8(ra[0], ra[1]);                               \
        *(f16x8*)(da + 8) = cvt8(ra[2], ra[3]);                               \
        *(f16x8*)db       = cvt8(rb[0], rb[1]);                               \
        *(f16x8*)(db + 8) = cvt8(rb[2], rb[3]);                               \
    } while (0)

    f32x4 acc[2][4] = {};
    GLOAD(0);
    DSWRITE(0);
    __syncthreads();
    int cur = 0;
    for (int kt = 0; kt < NKT; ++kt) {
        if (kt + 1 < NKT) GLOAD(kt + 1);          // issue early (under MFMA)
        __builtin_amdgcn_sched_barrier(0);
        #pragma unroll
        for (int ks = 0; ks < 2; ++ks) {
            f16x8 af[2], bf[4];
            #pragma unroll
            for (int i = 0; i < 2; ++i) {
                int r1 = wr * 32 + i * 16 + fr;
                af[i] = *(const f16x8*)&AsB[cur * NBH + r1 * LDH + ks * 32 + fg * 8];
            }
            #pragma unroll
            for (int j = 0; j < 4; ++j) {
                int r2 = wc * 64 + j * 16 + fr;
                bf[j] = *(const f16x8*)&BsB[cur * NBH + r2 * LDH + ks * 32 + fg * 8];
            }
            #pragma unroll
            for (int i = 0; i < 2; ++i)
                #pragma unroll
                for (int j = 0; j < 4; ++j)
                    acc[i][j] = __builtin_amdgcn_mfma_f32_16x16x32_f16(af[i], bf[j], acc[i][j], 0, 0, 0);
        }
        __builtin_amdgcn_sched_barrier(0);
        if (kt + 1 < NKT) DSWRITE(cur ^ 1);       // vmcnt wait lands here only
        __syncthreads();
        cur ^= 1;
    }
    #undef GLOAD
    #undef DSWRITE

    // block-local masked row/col max (C/D layout: row = fg*4+reg +16i, col = fr +16j)
    #pragma unroll
    for (int i = 0; i < 2; ++i)
        #pragma unroll
        for (int r = 0; r < 4; ++r) {
            int row = wr * 32 + i * 16 + fg * 4 + r;
            bool rv = m1s[row] > 0.f;
            float mx = NEGV;
            #pragma unroll
            for (int j = 0; j < 4; ++j) {
                int col = wc * 64 + j * 16 + fr;
                float vv = (rv && m2s[col] > 0.f) ? acc[i][j][r] : NEGV;
                mx = fmaxf(mx, vv);
            }
            atomicMax(&rU[row], fmap(mx));
        }
    #pragma unroll
    for (int j = 0; j < 4; ++j) {
        int col = wc * 64 + j * 16 + fr;
        bool cv = m2s[col] > 0.f;
        float mx = NEGV;
        #pragma unroll
        for (int i = 0; i < 2; ++i)
            #pragma unroll
            for (int r = 0; r < 4; ++r) {
                int row = wr * 32 + i * 16 + fg * 4 + r;
                float vv = (cv && m1s[row] > 0.f) ? acc[i][j][r] : NEGV;
                mx = fmaxf(mx, vv);
            }
        atomicMax(&cU[col], fmap(mx));
    }
    __syncthreads();

    // publish PARTIAL maxes (plain stores; each slot written by exactly one block)
    if (t < BT)            rmax_p[((size_t)b * 2 + tj) * L_ + ti * BT + t]        = fdecode(rU[t]);
    else if (t < 2 * BT)   cmax_p[((size_t)b * 2 + ti) * L_ + tj * BT + (t - BT)] = fdecode(cU[t - BT]);
    __threadfence();                              // per-thread release of its stores
    __syncthreads();

    // arrival + spin until all 4 sibling blocks published (all blocks resident:
    // grid 512 == 2/CU x 256 CU at LDS 76KB -> no deadlock)
    if (t == 0) {
        atomicAdd(&cnt[b], 1u);
        while (__hip_atomic_load(&cnt[b], __ATOMIC_ACQUIRE, __HIP_MEMORY_SCOPE_AGENT) < 4u)
            __builtin_amdgcn_s_sleep(2);
    }
    __syncthreads();

    // ---- phase 2 (all 4 blocks per batch): softmax both sides + pool chunk + cosine ----
    float* attnb = (float*)smem;                  // [2][256]  (aliases AsB)
    float* pbuf  = (float*)(smem + 2048);         // [2][192]
    const int h = t >> 8;                         // side: 0 (v1/rows) or 1 (v2/cols)
    const int l = t & 255;
    const int q = ti * 2 + tj;                    // this block's dim-chunk

    volatile const float* rp = rmax_p + (size_t)b * 2 * L_;
    volatile const float* cp = cmax_p + (size_t)b * 2 * L_;
    float mkv = (h ? m2 : m1)[b * L_ + l];
    float mxv = h ? fmaxf(cp[l], cp[L_ + l]) : fmaxf(rp[l], rp[L_ + l]);
    float s = (mkv > 0.f) ? (-mxv * 0.01f) : NEGV;

    // softmax within each 256-thread half (waves 0-3 = side 0, waves 4-7 = side 1)
    float wm = wred_max(s);
    if (lane == 0) sred[w] = wm;
    __syncthreads();
    float mx = fmaxf(fmaxf(sred[h * 4 + 0], sred[h * 4 + 1]),
                     fmaxf(sred[h * 4 + 2], sred[h * 4 + 3]));
    float e = expf(s - mx);
    __syncthreads();
    float wsum = wred_sum(e);
    if (lane == 0) sred[w] = wsum;
    __syncthreads();
    float sum = sred[h * 4 + 0] + sred[h * 4 + 1] + sred[h * 4 + 2] + sred[h * 4 + 3];
    attnb[h * 256 + l] = e / sum;
    __syncthreads();

    // pool: side h, dims q*192 + [0,192)  (coalesced 768B/row per half-block)
    if (l < 192) {
        int d = q * 192 + l;
        const float* vb = (h ? v2 : v1) + (size_t)b * L_ * D_ + d;
        const float* an = attnb + h * 256;
        float p = 0.f;
        #pragma unroll 8
        for (int ll = 0; ll < L_; ++ll) p += an[ll] * vb[(size_t)ll * D_];
        pbuf[h * 192 + l] = p;
    }
    __syncthreads();

    // partial cosine sums over this block's 192 dims
    float dotv = 0.f, n1v = 0.f, n2v = 0.f;
    if (t < 192) {
        float a = pbuf[t], c = pbuf[192 + t];
        dotv = a * c; n1v = a * a; n2v = c * c;
    }
    dotv = wred_sum(dotv); n1v = wred_sum(n1v); n2v = wred_sum(n2v);
    if (lane == 0) { sd[w] = dotv; sa[w] = n1v; sc2[w] = n2v; }
    __syncthreads();

    if (t == 0) {
        float dd = 0.f, aa = 0.f, cc = 0.f;
        #pragma unroll
        for (int i = 0; i < 8; ++i) { dd += sd[i]; aa += sa[i]; cc += sc2[i]; }
        float* gp = gpart + ((size_t)b * 4 + q) * 3;
        gp[0] = dd; gp[1] = aa; gp[2] = cc;
        __threadfence();
        unsigned old = atomicAdd(&cnt2[b], 1u);
        if (old == 3u) {                          // last arriver combines
            __threadfence();
            volatile const float* g0 = gpart + (size_t)b * 12;
            float DD = 0.f, AA = 0.f, CC = 0.f;
            #pragma unroll
            for (int i = 0; i < 4; ++i) {
                DD += g0[i * 3 + 0]; AA += g0[i * 3 + 1]; CC += g0[i * 3 + 2];
            }
            out[b] = DD / (fmaxf(sqrtf(AA), 1e-8f) * fmaxf(sqrtf(CC), 1e-8f));
        }
    }
}

extern "C" void kernel_launch(void* const* d_in, const int* in_sizes, int n_in,
                              void* d_out, int out_size, void* d_ws, size_t ws_size,
                              hipStream_t stream)
{
    const float* v1 = (const float*)d_in[0];
    const float* m1 = (const float*)d_in[1];
    const float* v2 = (const float*)d_in[2];
    const float* m2 = (const float*)d_in[3];
    float* out = (float*)d_out;

    unsigned* cnt    = (unsigned*)d_ws;                    // [B] phase-1 arrivals
    unsigned* cnt2   = cnt + B_;                           // [B] phase-2 arrivals
    float*    rmax_p = (float*)(cnt2 + B_);                // [B][2][256] row-max partials
    float*    cmax_p = rmax_p + (size_t)B_ * 2 * L_;       // [B][2][256] col-max partials
    float*    gpart  = cmax_p + (size_t)B_ * 2 * L_;       // [B][4][3] cosine partials

    (void)hipMemsetAsync(d_ws, 0, 2 * B_ * sizeof(unsigned), stream);  // counters only

    k_fused<<<dim3(4 * B_), 512, 0, stream>>>(v1, m1, v2, m2, rmax_p, cmax_p, gpart,
                                              cnt, cnt2, out);
}

// Round 9
// 83.620 us; speedup vs baseline: 2.1166x; 2.0859x over previous
//
#include <hip/hip_runtime.h>

// ParaModel_69664369541839: match = v1 @ v2^T [B,L1,L2]; masked row/col max;
// s = -max/100 masked; softmax; attention-pool p1,p2; cosine(p1,p2).
// B=128, L1=L2=256, D=768, fp32 in/out.
//
// R9: BLOCK-LOCAL fusion. R7/R8 proved cross-block handoff poisons the XCD
// L2s (device-scope acquire/release invalidates the whole local L2 -> 920GB/s).
// Timed-regime analysis: pipeline is Infinity-Cache-BW bound (~11 TB/s, from
// K2: 201MB/18us); the lever is bytes. One block per batch (grid 128 x 1024):
// phase 1 = 256x256 match tile, each input element read ONCE (402->201 MB);
// phase 2 = softmax+pool+cosine entirely in-block (no fences, no ws, no
// memset, 1 launch). Total bytes 603->402 MB.

#define B_   128
#define L_   256
#define D_   768
#define NEGV (-10000.0f)

typedef _Float16 f16x8 __attribute__((ext_vector_type(8)));
typedef __fp16   h16x2 __attribute__((ext_vector_type(2)));
typedef float    f32x4 __attribute__((ext_vector_type(4)));

#define BKF  32           // fp32 k-elems per staged tile (one MFMA K-step)
#define NKT  (D_ / BKF)   // 24
#define LDH  36           // halves per LDS row (72B: ~2-way bank spread, R6-style)

__device__ __forceinline__ unsigned fmap(float f) {
    unsigned u = __float_as_uint(f);
    return (u & 0x80000000u) ? ~u : (u | 0x80000000u);   // monotone float->uint
}
__device__ __forceinline__ float fdecode(unsigned u) {
    return __uint_as_float((u & 0x80000000u) ? (u ^ 0x80000000u) : ~u);
}
__device__ __forceinline__ float wred_max(float v) {
    #pragma unroll
    for (int o = 32; o; o >>= 1) v = fmaxf(v, __shfl_xor(v, o));
    return v;
}
__device__ __forceinline__ float wred_sum(float v) {
    #pragma unroll
    for (int o = 32; o; o >>= 1) v += __shfl_xor(v, o);
    return v;
}
__device__ __forceinline__ f16x8 cvt8(float4 a, float4 b) {
    union { h16x2 h2[4]; f16x8 h8; } u;
    u.h2[0] = __builtin_amdgcn_cvt_pkrtz(a.x, a.y);
    u.h2[1] = __builtin_amdgcn_cvt_pkrtz(a.z, a.w);
    u.h2[2] = __builtin_amdgcn_cvt_pkrtz(b.x, b.y);
    u.h2[3] = __builtin_amdgcn_cvt_pkrtz(b.z, b.w);
    return u.h8;
}

__global__ __launch_bounds__(1024, 4)
void k_all(const float* __restrict__ v1, const float* __restrict__ m1,
           const float* __restrict__ v2, const float* __restrict__ m2,
           float* __restrict__ out)
{
    __shared__ __align__(16) _Float16 As[2][L_ * LDH];   // 2 x 18 KB
    __shared__ __align__(16) _Float16 Bs[2][L_ * LDH];   // 2 x 18 KB
    __shared__ unsigned rU[L_], cU[L_];
    __shared__ float m1s[L_], m2s[L_];
    __shared__ float attn[2][L_];
    __shared__ float pbuf[2][D_];
    __shared__ float sred[16], sd[16], sa[16], sc2[16];

    const int b = blockIdx.x;                 // one block per batch
    const int t = threadIdx.x;
    const int lane = t & 63, w = t >> 6;      // 16 waves
    const int wr = w >> 2, wc = w & 3;        // wave tile: 64x64 in 256x256
    const int fr = lane & 15, fg = lane >> 4;

    if (t < L_) {
        rU[t] = 0u; cU[t] = 0u;               // 0 == -inf under fmap
        m1s[t] = m1[b * L_ + t];
        m2s[t] = m2[b * L_ + t];
    }

    // staging: thread t owns row (t>>2), fp32 cols [c4*8, c4*8+8) of each k-tile
    const int grow = t >> 2;                  // 0..255
    const int c4   = t & 3;
    const float* ga = v1 + ((size_t)b * L_ + grow) * D_ + c4 * 8;
    const float* gb = v2 + ((size_t)b * L_ + grow) * D_ + c4 * 8;

    float4 ra[2], rb[2];                      // 4 float4 in flight (16 VGPR)

    #define GLOAD(kt) do {                                                    \
        const float* A_ = ga + (kt) * BKF;                                    \
        const float* C_ = gb + (kt) * BKF;                                    \
        ra[0] = *(const float4*)(A_);  ra[1] = *(const float4*)(A_ + 4);      \
        rb[0] = *(const float4*)(C_);  rb[1] = *(const float4*)(C_ + 4);      \
    } while (0)

    #define DSWRITE(buf) do {                                                 \
        *(f16x8*)&As[buf][grow * LDH + c4 * 8] = cvt8(ra[0], ra[1]);          \
        *(f16x8*)&Bs[buf][grow * LDH + c4 * 8] = cvt8(rb[0], rb[1]);          \
    } while (0)

    f32x4 acc[4][4] = {};
    GLOAD(0);
    DSWRITE(0);
    __syncthreads();
    int cur = 0;
    for (int kt = 0; kt < NKT; ++kt) {
        if (kt + 1 < NKT) GLOAD(kt + 1);      // issue next tile early
        __builtin_amdgcn_sched_barrier(0);    // keep loads above the MFMA phase
        f16x8 af[4], bf[4];
        #pragma unroll
        for (int i = 0; i < 4; ++i)
            af[i] = *(const f16x8*)&As[cur][(wr * 64 + i * 16 + fr) * LDH + fg * 8];
        #pragma unroll
        for (int j = 0; j < 4; ++j)
            bf[j] = *(const f16x8*)&Bs[cur][(wc * 64 + j * 16 + fr) * LDH + fg * 8];
        #pragma unroll
        for (int i = 0; i < 4; ++i)
            #pragma unroll
            for (int j = 0; j < 4; ++j)
                acc[i][j] = __builtin_amdgcn_mfma_f32_16x16x32_f16(af[i], bf[j], acc[i][j], 0, 0, 0);
        __builtin_amdgcn_sched_barrier(0);    // cvt/ds_write stay after MFMAs
        if (kt + 1 < NKT) DSWRITE(cur ^ 1);   // vmcnt wait lands only here
        __syncthreads();
        cur ^= 1;
    }
    #undef GLOAD
    #undef DSWRITE

    // masked row/col max (C/D: row = wr*64 + i*16 + fg*4 + r, col = wc*64 + j*16 + fr)
    #pragma unroll
    for (int i = 0; i < 4; ++i)
        #pragma unroll
        for (int r = 0; r < 4; ++r) {
            int row = wr * 64 + i * 16 + fg * 4 + r;
            bool rv = m1s[row] > 0.f;
            float mx = NEGV;
            #pragma unroll
            for (int j = 0; j < 4; ++j) {
                int col = wc * 64 + j * 16 + fr;
                float vv = (rv && m2s[col] > 0.f) ? acc[i][j][r] : NEGV;
                mx = fmaxf(mx, vv);
            }
            atomicMax(&rU[row], fmap(mx));
        }
    #pragma unroll
    for (int j = 0; j < 4; ++j) {
        int col = wc * 64 + j * 16 + fr;
        bool cv = m2s[col] > 0.f;
        float mx = NEGV;
        #pragma unroll
        for (int i = 0; i < 4; ++i)
            #pragma unroll
            for (int r = 0; r < 4; ++r) {
                int row = wr * 64 + i * 16 + fg * 4 + r;
                float vv = (cv && m1s[row] > 0.f) ? acc[i][j][r] : NEGV;
                mx = fmaxf(mx, vv);
            }
        atomicMax(&cU[col], fmap(mx));
    }
    __syncthreads();

    // ---- phase 2 (block-local): softmax both sides -> pool -> cosine ----
    // softmax: threads 0..511 (waves 0-3 side 0, waves 4-7 side 1)
    {
        const int h = t >> 8, l = t & 255;
        float s = NEGV;
        if (t < 512) {
            float mkv = h ? m2s[l] : m1s[l];
            float mxv = fdecode(h ? cU[l] : rU[l]);
            s = (mkv > 0.f) ? (-mxv * 0.01f) : NEGV;
        }
        float wm = wred_max(s);
        if (lane == 0) sred[w] = wm;
        __syncthreads();
        if (t < 512) {
            float mx = fmaxf(fmaxf(sred[h * 4 + 0], sred[h * 4 + 1]),
                             fmaxf(sred[h * 4 + 2], sred[h * 4 + 3]));
            s = expf(s - mx);
        } else s = 0.f;
        __syncthreads();
        float ws = wred_sum(s);
        if (lane == 0) sred[w] = ws;
        __syncthreads();
        if (t < 512) {
            float sum = sred[h * 4 + 0] + sred[h * 4 + 1] + sred[h * 4 + 2] + sred[h * 4 + 3];
            attn[h][l] = s / sum;
        }
        __syncthreads();
    }

    // pool: 1536 (side,dim) pairs over 1024 threads, 2 rounds, coalesced
    {
        const float* vb1 = v1 + (size_t)b * L_ * D_;
        const float* vb2 = v2 + (size_t)b * L_ * D_;
        // round 1: t<768 -> (side0, d=t); t>=768 -> (side1, d=t-768)
        {
            const int h = (t < D_) ? 0 : 1;
            const int d = (t < D_) ? t : t - D_;
            const float* vb = (h ? vb2 : vb1) + d;
            const float* an = attn[h];
            float p = 0.f;
            #pragma unroll 8
            for (int l = 0; l < L_; ++l) p += an[l] * vb[(size_t)l * D_];
            pbuf[h][d] = p;
        }
        // round 2: t<512 -> (side1, d=256+t)
        if (t < 512) {
            const int d = 256 + t;
            const float* vb = vb2 + d;
            const float* an = attn[1];
            float p = 0.f;
            #pragma unroll 8
            for (int l = 0; l < L_; ++l) p += an[l] * vb[(size_t)l * D_];
            pbuf[1][d] = p;
        }
        __syncthreads();
    }

    // cosine similarity
    {
        float dot = 0.f, n1 = 0.f, n2 = 0.f;
        if (t < D_) {
            float a = pbuf[0][t], c = pbuf[1][t];
            dot = a * c; n1 = a * a; n2 = c * c;
        }
        dot = wred_sum(dot); n1 = wred_sum(n1); n2 = wred_sum(n2);
        if (lane == 0) { sd[w] = dot; sa[w] = n1; sc2[w] = n2; }
        __syncthreads();
        if (t == 0) {
            float dd = 0.f, aa = 0.f, cc = 0.f;
            #pragma unroll
            for (int i = 0; i < 16; ++i) { dd += sd[i]; aa += sa[i]; cc += sc2[i]; }
            out[b] = dd / (fmaxf(sqrtf(aa), 1e-8f) * fmaxf(sqrtf(cc), 1e-8f));
        }
    }
}

extern "C" void kernel_launch(void* const* d_in, const int* in_sizes, int n_in,
                              void* d_out, int out_size, void* d_ws, size_t ws_size,
                              hipStream_t stream)
{
    const float* v1 = (const float*)d_in[0];
    const float* m1 = (const float*)d_in[1];
    const float* v2 = (const float*)d_in[2];
    const float* m2 = (const float*)d_in[3];
    float* out = (float*)d_out;

    k_all<<<dim3(B_), 1024, 0, stream>>>(v1, m1, v2, m2, out);
}

// Round 10
// 73.987 us; speedup vs baseline: 2.3921x; 1.1302x over previous
//
#include <hip/hip_runtime.h>

// ParaModel_69664369541839: match = v1 @ v2^T [B,L1,L2]; masked row/col max;
// s = -max/100 masked; softmax; attention-pool p1,p2; cosine(p1,p2).
// B=128, L1=L2=256, D=768, fp32 in/out.
//
// R10: 3-kernel pipeline (fusion dead-ends: cross-block sync poisons XCD L2s
// [R7/R8]; block-local caps at 128 CUs [R9]). K1 re-partitioned to kill the
// last redundant bytes: 256 blocks = (b, row-half), each 128x256 tile ->
// v1 read once, v2 twice (402->295 MB). Row-max complete in-block (plain
// store); col-max = 2 partials combined by K2 (kernel-boundary coherence).
// No global atomics, no memset, no workspace counters. 1024 thr / 16 waves,
// BKF=64, LDH=72 (R6-verified bank pattern), reg-staged fp16 + sched_barrier
// pins. Per-thread stage = 6 float4 (24 VGPR) - trivially kept in flight.

#define B_   128
#define L_   256
#define D_   768
#define NEGV (-10000.0f)

typedef _Float16 f16x8 __attribute__((ext_vector_type(8)));
typedef __fp16   h16x2 __attribute__((ext_vector_type(2)));
typedef float    f32x4 __attribute__((ext_vector_type(4)));

#define BTR  128          // rows per block (half of L1)
#define BKF  64           // fp32 k-elems per staged tile (2 MFMA K-steps)
#define NKT  (D_ / BKF)   // 12
#define LDH  72           // halves per LDS row (144B: uniform bank spread)

__device__ __forceinline__ unsigned fmap(float f) {
    unsigned u = __float_as_uint(f);
    return (u & 0x80000000u) ? ~u : (u | 0x80000000u);   // monotone float->uint
}
__device__ __forceinline__ float fdecode(unsigned u) {
    return __uint_as_float((u & 0x80000000u) ? (u ^ 0x80000000u) : ~u);
}
__device__ __forceinline__ float wred_max(float v) {
    #pragma unroll
    for (int o = 32; o; o >>= 1) v = fmaxf(v, __shfl_xor(v, o));
    return v;
}
__device__ __forceinline__ float wred_sum(float v) {
    #pragma unroll
    for (int o = 32; o; o >>= 1) v += __shfl_xor(v, o);
    return v;
}
__device__ __forceinline__ f16x8 cvt8(float4 a, float4 b) {
    union { h16x2 h2[4]; f16x8 h8; } u;
    u.h2[0] = __builtin_amdgcn_cvt_pkrtz(a.x, a.y);
    u.h2[1] = __builtin_amdgcn_cvt_pkrtz(a.z, a.w);
    u.h2[2] = __builtin_amdgcn_cvt_pkrtz(b.x, b.y);
    u.h2[3] = __builtin_amdgcn_cvt_pkrtz(b.z, b.w);
    return u.h8;
}

// K1: per (b, rh): 128x256 match tile via fp16 MFMA.
// Row-max complete -> rmax[b][row]. Col-max partial -> cmax_p[b][rh][col].
__global__ __launch_bounds__(1024, 1)
void k_match(const float* __restrict__ v1, const float* __restrict__ m1,
             const float* __restrict__ v2, const float* __restrict__ m2,
             float* __restrict__ rmax, float* __restrict__ cmax_p)
{
    __shared__ __align__(16) _Float16 As[2][BTR * LDH];  // 2 x 18.4 KB
    __shared__ __align__(16) _Float16 Bs[2][L_ * LDH];   // 2 x 36.9 KB
    __shared__ unsigned rU[BTR], cU[L_];
    __shared__ float m1s[BTR], m2s[L_];

    // bijective XCD swizzle: 256 blocks, 32/XCD; a batch's 2 blocks adjacent
    const int bid = blockIdx.x;
    const int wg  = (bid & 7) * 32 + (bid >> 3);
    const int b = wg >> 1, rh = wg & 1;

    const int t = threadIdx.x;
    const int lane = t & 63, w = t >> 6;      // 16 waves
    const int wr = w >> 2, wc = w & 3;        // wave tile: 32 rows x 64 cols
    const int fr = lane & 15, fg = lane >> 4;

    if (t < BTR) { rU[t] = 0u; m1s[t] = m1[b * L_ + rh * BTR + t]; }
    if (t < L_)  { cU[t] = 0u; m2s[t] = m2[b * L_ + t]; }

    // staging: A tile 128x64 f32 -> thread owns row t>>3, cols (t&7)*8..+8
    //          B tile 256x64 f32 -> thread owns row t>>2, cols (t&3)*16..+16
    const int a_r = t >> 3, a_c = (t & 7) * 8;
    const int b_r = t >> 2, b_c = (t & 3) * 16;
    const float* ga = v1 + ((size_t)b * L_ + rh * BTR + a_r) * D_ + a_c;
    const float* gb = v2 + ((size_t)b * L_ + b_r) * D_ + b_c;

    float4 ra[2], rb[4];                      // 6 float4 in flight (24 VGPR)

    #define GLOAD(kt) do {                                                    \
        const float* A_ = ga + (kt) * BKF;                                    \
        const float* C_ = gb + (kt) * BKF;                                    \
        ra[0] = *(const float4*)(A_);      ra[1] = *(const float4*)(A_ + 4);  \
        rb[0] = *(const float4*)(C_);      rb[1] = *(const float4*)(C_ + 4);  \
        rb[2] = *(const float4*)(C_ + 8);  rb[3] = *(const float4*)(C_ + 12); \
    } while (0)

    #define DSWRITE(buf) do {                                                 \
        *(f16x8*)&As[buf][a_r * LDH + a_c] = cvt8(ra[0], ra[1]);              \
        _Float16* db = &Bs[buf][b_r * LDH + b_c];                             \
        *(f16x8*)db       = cvt8(rb[0], rb[1]);                               \
        *(f16x8*)(db + 8) = cvt8(rb[2], rb[3]);                               \
    } while (0)

    f32x4 acc[2][4] = {};
    GLOAD(0);
    DSWRITE(0);
    __syncthreads();
    int cur = 0;
    for (int kt = 0; kt < NKT; ++kt) {
        if (kt + 1 < NKT) GLOAD(kt + 1);      // issue next tile early
        __builtin_amdgcn_sched_barrier(0);    // keep loads above the MFMA phase
        #pragma unroll
        for (int ks = 0; ks < 2; ++ks) {
            f16x8 af[2], bf[4];
            #pragma unroll
            for (int i = 0; i < 2; ++i) {
                int r1 = wr * 32 + i * 16 + fr;
                af[i] = *(const f16x8*)&As[cur][r1 * LDH + ks * 32 + fg * 8];
            }
            #pragma unroll
            for (int j = 0; j < 4; ++j) {
                int r2 = wc * 64 + j * 16 + fr;
                bf[j] = *(const f16x8*)&Bs[cur][r2 * LDH + ks * 32 + fg * 8];
            }
            #pragma unroll
            for (int i = 0; i < 2; ++i)
                #pragma unroll
                for (int j = 0; j < 4; ++j)
                    acc[i][j] = __builtin_amdgcn_mfma_f32_16x16x32_f16(af[i], bf[j], acc[i][j], 0, 0, 0);
        }
        __builtin_amdgcn_sched_barrier(0);    // cvt/ds_write stay after MFMAs
        if (kt + 1 < NKT) DSWRITE(cur ^ 1);   // vmcnt wait lands only here
        __syncthreads();
        cur ^= 1;
    }
    #undef GLOAD
    #undef DSWRITE

    // masked row/col max (C/D: row = wr*32 + i*16 + fg*4 + r, col = wc*64 + j*16 + fr)
    #pragma unroll
    for (int i = 0; i < 2; ++i)
        #pragma unroll
        for (int r = 0; r < 4; ++r) {
            int row = wr * 32 + i * 16 + fg * 4 + r;
            bool rv = m1s[row] > 0.f;
            float mx = NEGV;
            #pragma unroll
            for (int j = 0; j < 4; ++j) {
                int col = wc * 64 + j * 16 + fr;
                float vv = (rv && m2s[col] > 0.f) ? acc[i][j][r] : NEGV;
                mx = fmaxf(mx, vv);
            }
            atomicMax(&rU[row], fmap(mx));    // LDS-local only
        }
    #pragma unroll
    for (int j = 0; j < 4; ++j) {
        int col = wc * 64 + j * 16 + fr;
        bool cv = m2s[col] > 0.f;
        float mx = NEGV;
        #pragma unroll
        for (int i = 0; i < 2; ++i)
            #pragma unroll
            for (int r = 0; r < 4; ++r) {
                int row = wr * 32 + i * 16 + fg * 4 + r;
                float vv = (cv && m1s[row] > 0.f) ? acc[i][j][r] : NEGV;
                mx = fmaxf(mx, vv);
            }
        atomicMax(&cU[col], fmap(mx));        // LDS-local only
    }
    __syncthreads();

    // complete row-max for this half (plain store); partial col-max per rh
    if (t < BTR)                rmax[b * L_ + rh * BTR + t] = fdecode(rU[t]);
    else if (t < BTR + L_)      cmax_p[((size_t)b * 2 + rh) * L_ + (t - BTR)] = fdecode(cU[t - BTR]);
}

// K2: per (b, side, chunk): softmax over 256 logits (redundant per chunk, cheap)
// + pool of 256 dims. 768 blocks.
__global__ __launch_bounds__(256)
void k_attn_pool(const float* __restrict__ v1, const float* __restrict__ m1,
                 const float* __restrict__ v2, const float* __restrict__ m2,
                 const float* __restrict__ rmax, const float* __restrict__ cmax_p,
                 float* __restrict__ pout)
{
    // XCD swizzle: 768 blocks -> 96/XCD -> consecutive batches per XCD
    const int lin = (int)blockIdx.x;
    const int swz = (lin & 7) * 96 + (lin >> 3);
    const int b = swz / 6, rem = swz % 6, side = rem / 3, chunk = rem % 3;

    const float* v  = side ? v2 : v1;
    const float* mk = side ? m2 : m1;
    const int t = threadIdx.x, lane = t & 63, w = t >> 6;

    __shared__ float attn[L_];
    __shared__ float sred[4];

    float mkv = mk[b * L_ + t];
    float mxv = side ? fmaxf(cmax_p[((size_t)b * 2) * L_ + t],
                             cmax_p[((size_t)b * 2 + 1) * L_ + t])
                     : rmax[b * L_ + t];
    float s = (mkv > 0.f) ? (-mxv * 0.01f) : NEGV;

    float wm = wred_max(s);
    if (lane == 0) sred[w] = wm;
    __syncthreads();
    float mx = fmaxf(fmaxf(sred[0], sred[1]), fmaxf(sred[2], sred[3]));
    float e = expf(s - mx);
    __syncthreads();
    float ws = wred_sum(e);
    if (lane == 0) sred[w] = ws;
    __syncthreads();
    float sum = sred[0] + sred[1] + sred[2] + sred[3];
    attn[t] = e / sum;
    __syncthreads();

    const int d = chunk * 256 + t;
    const float* vb = v + (size_t)b * L_ * D_ + d;
    float p = 0.f;
    #pragma unroll 8
    for (int l = 0; l < L_; ++l) p += attn[l] * vb[(size_t)l * D_];
    pout[((size_t)b * 2 + side) * D_ + d] = p;
}

// K3: per batch: cosine similarity of p1, p2.
__global__ __launch_bounds__(256)
void k_cos(const float* __restrict__ pout, float* __restrict__ out)
{
    const int b = blockIdx.x, t = threadIdx.x, lane = t & 63, w = t >> 6;
    const float* p1 = pout + (size_t)b * 2 * D_;
    const float* p2 = p1 + D_;
    float dot = 0.f, n1 = 0.f, n2 = 0.f;
    for (int d = t; d < D_; d += 256) {
        float a = p1[d], c = p2[d];
        dot += a * c; n1 += a * a; n2 += c * c;
    }
    dot = wred_sum(dot); n1 = wred_sum(n1); n2 = wred_sum(n2);
    __shared__ float sd[4], sa[4], sc[4];
    if (lane == 0) { sd[w] = dot; sa[w] = n1; sc[w] = n2; }
    __syncthreads();
    if (t == 0) {
        float dd = sd[0] + sd[1] + sd[2] + sd[3];
        float aa = sa[0] + sa[1] + sa[2] + sa[3];
        float cc = sc[0] + sc[1] + sc[2] + sc[3];
        out[b] = dd / (fmaxf(sqrtf(aa), 1e-8f) * fmaxf(sqrtf(cc), 1e-8f));
    }
}

extern "C" void kernel_launch(void* const* d_in, const int* in_sizes, int n_in,
                              void* d_out, int out_size, void* d_ws, size_t ws_size,
                              hipStream_t stream)
{
    const float* v1 = (const float*)d_in[0];
    const float* m1 = (const float*)d_in[1];
    const float* v2 = (const float*)d_in[2];
    const float* m2 = (const float*)d_in[3];
    float* out = (float*)d_out;

    float* rmax   = (float*)d_ws;                       // [B][256] complete row-max
    float* cmax_p = rmax + (size_t)B_ * L_;             // [B][2][256] col-max partials
    float* pout   = cmax_p + (size_t)B_ * 2 * L_;       // [B][2][768] pooled vectors

    k_match<<<dim3(2 * B_), 1024, 0, stream>>>(v1, m1, v2, m2, rmax, cmax_p);

    k_attn_pool<<<dim3(B_ * 2 * 3), 256, 0, stream>>>(v1, m1, v2, m2, rmax, cmax_p, pout);

    k_cos<<<B_, 256, 0, stream>>>(pout, out);
}

// Round 11
// 72.731 us; speedup vs baseline: 2.4335x; 1.0173x over previous
//
#include <hip/hip_runtime.h>

// ParaModel_69664369541839: match = v1 @ v2^T [B,L1,L2]; masked row/col max;
// s = -max/100 masked; softmax; attention-pool p1,p2; cosine(p1,p2).
// B=128, L1=L2=256, D=768, fp32 in/out.
//
// R11 = R10 + T4 "counted vmcnt": 2-deep register staging in K1. Evidence:
// R10 cut bytes 27% but K1 moved only 8% -> K1 is NOT mem-BW-bound; it's the
// m233 2-phase stall (stage+vmcnt+barrier overhead, payload-independent).
// Fix per m218: keep loads in flight ACROSS barriers. Two named load-sets;
// at iter kt: GLOAD(set kt&1, tile kt+2) -> compute -> DSWRITE(other set =
// tile kt+1) whose register deps give vmcnt(6), never vmcnt(0). Sets selected
// by static even/odd bodies (rule #20). LDS 113KB fixes occupancy at 1 blk/CU
// so the allocator has no incentive to sink the 48 staging VGPRs.

#define B_   128
#define L_   256
#define D_   768
#define NEGV (-10000.0f)

typedef _Float16 f16x8 __attribute__((ext_vector_type(8)));
typedef __fp16   h16x2 __attribute__((ext_vector_type(2)));
typedef float    f32x4 __attribute__((ext_vector_type(4)));

#define BTR  128          // rows per block (half of L1)
#define BKF  64           // fp32 k-elems per staged tile (2 MFMA K-steps)
#define NKT  (D_ / BKF)   // 12 (even)
#define LDH  72           // halves per LDS row (144B: uniform bank spread)

__device__ __forceinline__ unsigned fmap(float f) {
    unsigned u = __float_as_uint(f);
    return (u & 0x80000000u) ? ~u : (u | 0x80000000u);   // monotone float->uint
}
__device__ __forceinline__ float fdecode(unsigned u) {
    return __uint_as_float((u & 0x80000000u) ? (u ^ 0x80000000u) : ~u);
}
__device__ __forceinline__ float wred_max(float v) {
    #pragma unroll
    for (int o = 32; o; o >>= 1) v = fmaxf(v, __shfl_xor(v, o));
    return v;
}
__device__ __forceinline__ float wred_sum(float v) {
    #pragma unroll
    for (int o = 32; o; o >>= 1) v += __shfl_xor(v, o);
    return v;
}
__device__ __forceinline__ f16x8 cvt8(float4 a, float4 b) {
    union { h16x2 h2[4]; f16x8 h8; } u;
    u.h2[0] = __builtin_amdgcn_cvt_pkrtz(a.x, a.y);
    u.h2[1] = __builtin_amdgcn_cvt_pkrtz(a.z, a.w);
    u.h2[2] = __builtin_amdgcn_cvt_pkrtz(b.x, b.y);
    u.h2[3] = __builtin_amdgcn_cvt_pkrtz(b.z, b.w);
    return u.h8;
}

// K1: per (b, rh): 128x256 match tile via fp16 MFMA.
// Row-max complete -> rmax[b][row]. Col-max partial -> cmax_p[b][rh][col].
__global__ __launch_bounds__(1024, 1)
void k_match(const float* __restrict__ v1, const float* __restrict__ m1,
             const float* __restrict__ v2, const float* __restrict__ m2,
             float* __restrict__ rmax, float* __restrict__ cmax_p)
{
    __shared__ __align__(16) _Float16 As[2][BTR * LDH];  // 2 x 18.4 KB
    __shared__ __align__(16) _Float16 Bs[2][L_ * LDH];   // 2 x 36.9 KB
    __shared__ unsigned rU[BTR], cU[L_];
    __shared__ float m1s[BTR], m2s[L_];

    // bijective XCD swizzle: 256 blocks, 32/XCD; a batch's 2 blocks adjacent
    const int bid = blockIdx.x;
    const int wg  = (bid & 7) * 32 + (bid >> 3);
    const int b = wg >> 1, rh = wg & 1;

    const int t = threadIdx.x;
    const int lane = t & 63, w = t >> 6;      // 16 waves
    const int wr = w >> 2, wc = w & 3;        // wave tile: 32 rows x 64 cols
    const int fr = lane & 15, fg = lane >> 4;

    if (t < BTR) { rU[t] = 0u; m1s[t] = m1[b * L_ + rh * BTR + t]; }
    if (t < L_)  { cU[t] = 0u; m2s[t] = m2[b * L_ + t]; }

    // staging: A tile 128x64 f32 -> thread owns row t>>3, cols (t&7)*8..+8
    //          B tile 256x64 f32 -> thread owns row t>>2, cols (t&3)*16..+16
    const int a_r = t >> 3, a_c = (t & 7) * 8;
    const int b_r = t >> 2, b_c = (t & 3) * 16;
    const float* ga = v1 + ((size_t)b * L_ + rh * BTR + a_r) * D_ + a_c;
    const float* gb = v2 + ((size_t)b * L_ + b_r) * D_ + b_c;

    // TWO named staging sets (2-deep pipeline, 12 float4 = 48 VGPR)
    float4 raA[2], rbA[4], raB[2], rbB[4];

    #define GLOADS(RA, RB, kt) do {                                           \
        const float* A_ = ga + (kt) * BKF;                                    \
        const float* C_ = gb + (kt) * BKF;                                    \
        RA[0] = *(const float4*)(A_);      RA[1] = *(const float4*)(A_ + 4);  \
        RB[0] = *(const float4*)(C_);      RB[1] = *(const float4*)(C_ + 4);  \
        RB[2] = *(const float4*)(C_ + 8);  RB[3] = *(const float4*)(C_ + 12); \
    } while (0)

    #define DSWRITES(RA, RB, buf) do {                                        \
        *(f16x8*)&As[buf][a_r * LDH + a_c] = cvt8(RA[0], RA[1]);              \
        _Float16* db = &Bs[buf][b_r * LDH + b_c];                             \
        *(f16x8*)db       = cvt8(RB[0], RB[1]);                               \
        *(f16x8*)(db + 8) = cvt8(RB[2], RB[3]);                               \
    } while (0)

    #define COMPUTE(buf) do {                                                 \
        _Pragma("unroll")                                                     \
        for (int ks = 0; ks < 2; ++ks) {                                      \
            f16x8 af[2], bf[4];                                               \
            _Pragma("unroll")                                                 \
            for (int i = 0; i < 2; ++i) {                                     \
                int r1 = wr * 32 + i * 16 + fr;                               \
                af[i] = *(const f16x8*)&As[buf][r1 * LDH + ks * 32 + fg * 8]; \
            }                                                                 \
            _Pragma("unroll")                                                 \
            for (int j = 0; j < 4; ++j) {                                     \
                int r2 = wc * 64 + j * 16 + fr;                               \
                bf[j] = *(const f16x8*)&Bs[buf][r2 * LDH + ks * 32 + fg * 8]; \
            }                                                                 \
            _Pragma("unroll")                                                 \
            for (int i = 0; i < 2; ++i)                                       \
                _Pragma("unroll")                                             \
                for (int j = 0; j < 4; ++j)                                   \
                    acc[i][j] = __builtin_amdgcn_mfma_f32_16x16x32_f16(af[i], bf[j], acc[i][j], 0, 0, 0); \
        }                                                                     \
    } while (0)

    f32x4 acc[2][4] = {};
    GLOADS(raA, rbA, 0);                      // tile 0 -> set A
    GLOADS(raB, rbB, 1);                      // tile 1 -> set B (in flight)
    DSWRITES(raA, rbA, 0);                    // tile 0 -> buf 0 (vmcnt(6): B outstanding)
    __syncthreads();
    int cur = 0;
    #pragma unroll
    for (int kp = 0; kp < NKT; kp += 2) {
        // ---- even iter: kt = kp (compute tile kp from buf cur) ----
        if (kp + 2 < NKT) GLOADS(raA, rbA, kp + 2);   // set A free, load tile kp+2
        __builtin_amdgcn_sched_barrier(0);
        COMPUTE(cur);
        __builtin_amdgcn_sched_barrier(0);
        DSWRITES(raB, rbB, cur ^ 1);                  // tile kp+1; waits only set B -> vmcnt(6)
        __syncthreads();
        cur ^= 1;
        // ---- odd iter: kt = kp+1 ----
        if (kp + 3 < NKT) GLOADS(raB, rbB, kp + 3);   // set B free, load tile kp+3
        __builtin_amdgcn_sched_barrier(0);
        COMPUTE(cur);
        __builtin_amdgcn_sched_barrier(0);
        if (kp + 2 < NKT) DSWRITES(raA, rbA, cur ^ 1);// tile kp+2; vmcnt(6)
        __syncthreads();
        cur ^= 1;
    }
    #undef GLOADS
    #undef DSWRITES
    #undef COMPUTE

    // masked row/col max (C/D: row = wr*32 + i*16 + fg*4 + r, col = wc*64 + j*16 + fr)
    #pragma unroll
    for (int i = 0; i < 2; ++i)
        #pragma unroll
        for (int r = 0; r < 4; ++r) {
            int row = wr * 32 + i * 16 + fg * 4 + r;
            bool rv = m1s[row] > 0.f;
            float mx = NEGV;
            #pragma unroll
            for (int j = 0; j < 4; ++j) {
                int col = wc * 64 + j * 16 + fr;
                float vv = (rv && m2s[col] > 0.f) ? acc[i][j][r] : NEGV;
                mx = fmaxf(mx, vv);
            }
            atomicMax(&rU[row], fmap(mx));    // LDS-local only
        }
    #pragma unroll
    for (int j = 0; j < 4; ++j) {
        int col = wc * 64 + j * 16 + fr;
        bool cv = m2s[col] > 0.f;
        float mx = NEGV;
        #pragma unroll
        for (int i = 0; i < 2; ++i)
            #pragma unroll
            for (int r = 0; r < 4; ++r) {
                int row = wr * 32 + i * 16 + fg * 4 + r;
                float vv = (cv && m1s[row] > 0.f) ? acc[i][j][r] : NEGV;
                mx = fmaxf(mx, vv);
            }
        atomicMax(&cU[col], fmap(mx));        // LDS-local only
    }
    __syncthreads();

    // complete row-max for this half (plain store); partial col-max per rh
    if (t < BTR)                rmax[b * L_ + rh * BTR + t] = fdecode(rU[t]);
    else if (t < BTR + L_)      cmax_p[((size_t)b * 2 + rh) * L_ + (t - BTR)] = fdecode(cU[t - BTR]);
}

// K2: per (b, side, chunk): softmax over 256 logits (redundant per chunk, cheap)
// + pool of 256 dims. 768 blocks.
__global__ __launch_bounds__(256)
void k_attn_pool(const float* __restrict__ v1, const float* __restrict__ m1,
                 const float* __restrict__ v2, const float* __restrict__ m2,
                 const float* __restrict__ rmax, const float* __restrict__ cmax_p,
                 float* __restrict__ pout)
{
    // XCD swizzle: 768 blocks -> 96/XCD -> consecutive batches per XCD
    const int lin = (int)blockIdx.x;
    const int swz = (lin & 7) * 96 + (lin >> 3);
    const int b = swz / 6, rem = swz % 6, side = rem / 3, chunk = rem % 3;

    const float* v  = side ? v2 : v1;
    const float* mk = side ? m2 : m1;
    const int t = threadIdx.x, lane = t & 63, w = t >> 6;

    __shared__ float attn[L_];
    __shared__ float sred[4];

    float mkv = mk[b * L_ + t];
    float mxv = side ? fmaxf(cmax_p[((size_t)b * 2) * L_ + t],
                             cmax_p[((size_t)b * 2 + 1) * L_ + t])
                     : rmax[b * L_ + t];
    float s = (mkv > 0.f) ? (-mxv * 0.01f) : NEGV;

    float wm = wred_max(s);
    if (lane == 0) sred[w] = wm;
    __syncthreads();
    float mx = fmaxf(fmaxf(sred[0], sred[1]), fmaxf(sred[2], sred[3]));
    float e = expf(s - mx);
    __syncthreads();
    float ws = wred_sum(e);
    if (lane == 0) sred[w] = ws;
    __syncthreads();
    float sum = sred[0] + sred[1] + sred[2] + sred[3];
    attn[t] = e / sum;
    __syncthreads();

    const int d = chunk * 256 + t;
    const float* vb = v + (size_t)b * L_ * D_ + d;
    float p = 0.f;
    #pragma unroll 8
    for (int l = 0; l < L_; ++l) p += attn[l] * vb[(size_t)l * D_];
    pout[((size_t)b * 2 + side) * D_ + d] = p;
}

// K3: per batch: cosine similarity of p1, p2.
__global__ __launch_bounds__(256)
void k_cos(const float* __restrict__ pout, float* __restrict__ out)
{
    const int b = blockIdx.x, t = threadIdx.x, lane = t & 63, w = t >> 6;
    const float* p1 = pout + (size_t)b * 2 * D_;
    const float* p2 = p1 + D_;
    float dot = 0.f, n1 = 0.f, n2 = 0.f;
    for (int d = t; d < D_; d += 256) {
        float a = p1[d], c = p2[d];
        dot += a * c; n1 += a * a; n2 += c * c;
    }
    dot = wred_sum(dot); n1 = wred_sum(n1); n2 = wred_sum(n2);
    __shared__ float sd[4], sa[4], sc[4];
    if (lane == 0) { sd[w] = dot; sa[w] = n1; sc[w] = n2; }
    __syncthreads();
    if (t == 0) {
        float dd = sd[0] + sd[1] + sd[2] + sd[3];
        float aa = sa[0] + sa[1] + sa[2] + sa[3];
        float cc = sc[0] + sc[1] + sc[2] + sc[3];
        out[b] = dd / (fmaxf(sqrtf(aa), 1e-8f) * fmaxf(sqrtf(cc), 1e-8f));
    }
}

extern "C" void kernel_launch(void* const* d_in, const int* in_sizes, int n_in,
                              void* d_out, int out_size, void* d_ws, size_t ws_size,
                              hipStream_t stream)
{
    const float* v1 = (const float*)d_in[0];
    const float* m1 = (const float*)d_in[1];
    const float* v2 = (const float*)d_in[2];
    const float* m2 = (const float*)d_in[3];
    float* out = (float*)d_out;

    float* rmax   = (float*)d_ws;                       // [B][256] complete row-max
    float* cmax_p = rmax + (size_t)B_ * L_;             // [B][2][256] col-max partials
    float* pout   = cmax_p + (size_t)B_ * 2 * L_;       // [B][2][768] pooled vectors

    k_match<<<dim3(2 * B_), 1024, 0, stream>>>(v1, m1, v2, m2, rmax, cmax_p);

    k_attn_pool<<<dim3(B_ * 2 * 3), 256, 0, stream>>>(v1, m1, v2, m2, rmax, cmax_p, pout);

    k_cos<<<B_, 256, 0, stream>>>(pout, out);
}